// Round 1
// baseline (522.989 us; speedup 1.0000x reference)
//
#include <hip/hip_runtime.h>
#include <hip/hip_bf16.h>

// Problem constants
#define NROWS 50000
#define MOBS  2048
#define EDIM  512
#define ODIM  256

// ---------------------------------------------------------------------------
// G = obs^T @ obs   [256 x 256]
// ---------------------------------------------------------------------------
__global__ __launch_bounds__(256) void gram_kernel(const float* __restrict__ obs,
                                                   float* __restrict__ G) {
    __shared__ float As[16][17];
    __shared__ float Bs[16][17];
    const int tx = threadIdx.x, ty = threadIdx.y;
    const int i0 = blockIdx.y * 16, j0 = blockIdx.x * 16;
    float acc = 0.f;
    for (int m0 = 0; m0 < MOBS; m0 += 16) {
        As[ty][tx] = obs[(m0 + ty) * ODIM + i0 + tx];
        Bs[ty][tx] = obs[(m0 + ty) * ODIM + j0 + tx];
        __syncthreads();
#pragma unroll
        for (int p = 0; p < 16; ++p) acc += As[p][ty] * Bs[p][tx];
        __syncthreads();
    }
    G[(i0 + ty) * ODIM + (j0 + tx)] = acc;
}

// ---------------------------------------------------------------------------
// Generic small tiled GEMM: C[i,j] = sum_k Aval(i,k)*Bval(k,j)
//   TA=0: Aval = A[i*lda+k]    TA=1: Aval = A[k*lda+i]
//   TB=0: Bval = B[k*ldb+j]    TB=1: Bval = B[j*ldb+k]
// All dims multiples of 16.
// ---------------------------------------------------------------------------
template <int TA, int TB>
__global__ __launch_bounds__(256) void sgemm_t(const float* __restrict__ A,
                                               const float* __restrict__ B,
                                               float* __restrict__ C,
                                               int NN, int KK, int lda, int ldb) {
    __shared__ float As[16][17];
    __shared__ float Bs[16][17];
    const int tx = threadIdx.x, ty = threadIdx.y;
    const int i = blockIdx.y * 16 + ty;
    const int j = blockIdx.x * 16 + tx;
    float acc = 0.f;
    for (int k0 = 0; k0 < KK; k0 += 16) {
        As[ty][tx] = TA ? A[(k0 + tx) * lda + i] : A[i * lda + (k0 + tx)];
        Bs[ty][tx] = TB ? B[j * ldb + (k0 + ty)] : B[(k0 + ty) * ldb + j];
        __syncthreads();
#pragma unroll
        for (int p = 0; p < 16; ++p) acc += As[ty][p] * Bs[p][tx];
        __syncthreads();
    }
    C[i * NN + j] = acc;
}

// ---------------------------------------------------------------------------
// Big GEMM with fused residual:  out = node @ U + node   [50000 x 512]
// 128x128 tile, 256 threads, 8x8 micro-tile, K-tile = 16.
// ---------------------------------------------------------------------------
__global__ __launch_bounds__(256) void gemm_res(const float* __restrict__ node,
                                                const float* __restrict__ U,
                                                float* __restrict__ out) {
    __shared__ float As[16][132];   // [k][m], padded: row stride 528B (16B-mult)
    __shared__ float Bs[16][128];   // [k][n]
    const int t  = threadIdx.x;
    const int tx = t & 15, ty = t >> 4;
    const int m0 = blockIdx.y * 128, n0 = blockIdx.x * 128;

    float acc[8][8];
#pragma unroll
    for (int i2 = 0; i2 < 8; ++i2)
#pragma unroll
        for (int j2 = 0; j2 < 8; ++j2) acc[i2][j2] = 0.f;

    for (int k0 = 0; k0 < EDIM; k0 += 16) {
        // stage A: 128 rows x 16 k
#pragma unroll
        for (int p = 0; p < 8; ++p) {
            int m = (t >> 4) + 16 * p;
            int k = t & 15;
            int gr = m0 + m;
            As[k][m] = (gr < NROWS) ? node[gr * EDIM + k0 + k] : 0.f;
        }
        // stage B: 16 k x 128 n
#pragma unroll
        for (int p = 0; p < 8; ++p) {
            int k = (t >> 7) + 2 * p;
            int n = t & 127;
            Bs[k][n] = U[(k0 + k) * EDIM + n0 + n];
        }
        __syncthreads();
#pragma unroll
        for (int k = 0; k < 16; ++k) {
            float4 a0 = *(const float4*)&As[k][ty * 8];
            float4 a1 = *(const float4*)&As[k][ty * 8 + 4];
            float4 b0 = *(const float4*)&Bs[k][tx * 8];
            float4 b1 = *(const float4*)&Bs[k][tx * 8 + 4];
            float a[8] = {a0.x, a0.y, a0.z, a0.w, a1.x, a1.y, a1.z, a1.w};
            float b[8] = {b0.x, b0.y, b0.z, b0.w, b1.x, b1.y, b1.z, b1.w};
#pragma unroll
            for (int i2 = 0; i2 < 8; ++i2)
#pragma unroll
                for (int j2 = 0; j2 < 8; ++j2) acc[i2][j2] += a[i2] * b[j2];
        }
        __syncthreads();
    }

    // epilogue: add residual, store
#pragma unroll
    for (int i2 = 0; i2 < 8; ++i2) {
        int row = m0 + ty * 8 + i2;
        if (row < NROWS) {
            int cbase = row * EDIM + n0 + tx * 8;
            float4 r0 = *(const float4*)&node[cbase];
            float4 r1 = *(const float4*)&node[cbase + 4];
            float4 o0 = make_float4(acc[i2][0] + r0.x, acc[i2][1] + r0.y,
                                    acc[i2][2] + r0.z, acc[i2][3] + r0.w);
            float4 o1 = make_float4(acc[i2][4] + r1.x, acc[i2][5] + r1.y,
                                    acc[i2][6] + r1.z, acc[i2][7] + r1.w);
            *(float4*)&out[cbase]     = o0;
            *(float4*)&out[cbase + 4] = o1;
        }
    }
}

// ---------------------------------------------------------------------------
// In-place row LayerNorm over 512 cols. One wave (64 lanes) per row.
// ---------------------------------------------------------------------------
__global__ __launch_bounds__(256) void ln_kernel(float* __restrict__ out,
                                                 const float* __restrict__ gamma,
                                                 const float* __restrict__ beta) {
    const int wid  = threadIdx.x >> 6;
    const int lane = threadIdx.x & 63;
    const int row  = blockIdx.x * 4 + wid;
    if (row >= NROWS) return;
    float* rp = out + (size_t)row * EDIM;
    const int c0 = lane * 8;

    float4 v0 = *(const float4*)&rp[c0];
    float4 v1 = *(const float4*)&rp[c0 + 4];
    float x[8] = {v0.x, v0.y, v0.z, v0.w, v1.x, v1.y, v1.z, v1.w};

    float s = 0.f;
#pragma unroll
    for (int j = 0; j < 8; ++j) s += x[j];
#pragma unroll
    for (int off = 32; off > 0; off >>= 1) s += __shfl_xor(s, off);
    float mu = s * (1.f / 512.f);

    float vs = 0.f;
#pragma unroll
    for (int j = 0; j < 8; ++j) {
        float d = x[j] - mu;
        vs += d * d;
    }
#pragma unroll
    for (int off = 32; off > 0; off >>= 1) vs += __shfl_xor(vs, off);
    float inv = rsqrtf(vs * (1.f / 512.f) + 1e-6f);

    float y[8];
#pragma unroll
    for (int j = 0; j < 8; ++j)
        y[j] = (x[j] - mu) * inv * gamma[c0 + j] + beta[c0 + j];

    float4 o0 = make_float4(y[0], y[1], y[2], y[3]);
    float4 o1 = make_float4(y[4], y[5], y[6], y[7]);
    *(float4*)&rp[c0]     = o0;
    *(float4*)&rp[c0 + 4] = o1;
}

// ---------------------------------------------------------------------------
extern "C" void kernel_launch(void* const* d_in, const int* in_sizes, int n_in,
                              void* d_out, int out_size, void* d_ws, size_t ws_size,
                              hipStream_t stream) {
    const float* node  = (const float*)d_in[0];   // [N, E]
    const float* obs   = (const float*)d_in[1];   // [M, O]
    const float* Wq    = (const float*)d_in[2];   // [E, E]
    const float* Wk    = (const float*)d_in[3];   // [E, O]
    const float* Wv    = (const float*)d_in[4];   // [E, O]
    const float* gamma = (const float*)d_in[5];   // [E]
    const float* beta  = (const float*)d_in[6];   // [E]
    float* out = (float*)d_out;

    float* ws = (float*)d_ws;
    float* G  = ws;                  // 256*256
    float* T1 = G  + ODIM * ODIM;    // 256*512
    float* T2 = T1 + ODIM * EDIM;    // 512*512
    float* U  = T2 + EDIM * EDIM;    // 512*512

    dim3 b16(16, 16);

    // G = obs^T obs
    gram_kernel<<<dim3(16, 16), b16, 0, stream>>>(obs, G);
    // T1 = G @ Wv^T          [256 x 512], K=256.  Bval(k,e)=Wv[e*256+k] -> TB=1
    sgemm_t<0, 1><<<dim3(32, 16), b16, 0, stream>>>(G, Wv, T1, EDIM, ODIM, ODIM, ODIM);
    // T2 = Wk @ T1           [512 x 512], K=256
    sgemm_t<0, 0><<<dim3(32, 32), b16, 0, stream>>>(Wk, T1, T2, EDIM, ODIM, ODIM, EDIM);
    // U = Wq^T @ T2          [512 x 512], K=512.  Aval(b,a)=Wq[a*512+b] -> TA=1
    sgemm_t<1, 0><<<dim3(32, 32), b16, 0, stream>>>(Wq, T2, U, EDIM, EDIM, EDIM, EDIM);
    // out = node @ U + node
    gemm_res<<<dim3(4, 391), 256, 0, stream>>>(node, U, out);
    // in-place LN
    ln_kernel<<<12500, 256, 0, stream>>>(out, gamma, beta);
}

// Round 2
// 224.620 us; speedup vs baseline: 2.3283x; 2.3283x over previous
//
#include <hip/hip_runtime.h>
#include <hip/hip_bf16.h>

#define NROWS 50000
#define MOBS  2048
#define EDIM  512
#define ODIM  256

typedef short s16x8 __attribute__((ext_vector_type(8)));
typedef float f32x4 __attribute__((ext_vector_type(4)));

__device__ __forceinline__ unsigned short f32_to_bf16(float f) {
    unsigned int u = __float_as_uint(f);
    u += 0x7fffu + ((u >> 16) & 1u);     // RNE (inputs are finite/normal)
    return (unsigned short)(u >> 16);
}

// ---------------------------------------------------------------------------
// G += obs^T @ obs  (split-K over gridDim.z; G must be zeroed first)
// ---------------------------------------------------------------------------
__global__ __launch_bounds__(256) void gram_splitk(const float* __restrict__ obs,
                                                   float* __restrict__ G) {
    __shared__ float As[16][17];
    __shared__ float Bs[16][17];
    const int tx = threadIdx.x, ty = threadIdx.y;
    const int i0 = blockIdx.y * 16, j0 = blockIdx.x * 16;
    const int kbase = blockIdx.z * (MOBS / 8);
    float acc = 0.f;
    for (int m0 = kbase; m0 < kbase + MOBS / 8; m0 += 16) {
        As[ty][tx] = obs[(m0 + ty) * ODIM + i0 + tx];
        Bs[ty][tx] = obs[(m0 + ty) * ODIM + j0 + tx];
        __syncthreads();
#pragma unroll
        for (int p = 0; p < 16; ++p) acc += As[p][ty] * Bs[p][tx];
        __syncthreads();
    }
    atomicAdd(&G[(i0 + ty) * ODIM + (j0 + tx)], acc);
}

// ---------------------------------------------------------------------------
// Generic small tiled GEMM (fp32): C[i,j] = sum_k Aval(i,k)*Bval(k,j)
// ---------------------------------------------------------------------------
template <int TA, int TB>
__global__ __launch_bounds__(256) void sgemm_t(const float* __restrict__ A,
                                               const float* __restrict__ B,
                                               float* __restrict__ C,
                                               int NN, int KK, int lda, int ldb) {
    __shared__ float As[16][17];
    __shared__ float Bs[16][17];
    const int tx = threadIdx.x, ty = threadIdx.y;
    const int i = blockIdx.y * 16 + ty;
    const int j = blockIdx.x * 16 + tx;
    float acc = 0.f;
    for (int k0 = 0; k0 < KK; k0 += 16) {
        As[ty][tx] = TA ? A[(k0 + tx) * lda + i] : A[i * lda + (k0 + tx)];
        Bs[ty][tx] = TB ? B[j * ldb + (k0 + ty)] : B[(k0 + ty) * ldb + j];
        __syncthreads();
#pragma unroll
        for (int p = 0; p < 16; ++p) acc += As[ty][p] * Bs[p][tx];
        __syncthreads();
    }
    C[i * NN + j] = acc;
}

// ---------------------------------------------------------------------------
// Ut[b][a] = (bf16) sum_e Wq[e][a] * T2[e][b]   (i.e. U^T, U = Wq^T @ T2)
// ---------------------------------------------------------------------------
__global__ __launch_bounds__(256) void ugemm_bf16(const float* __restrict__ Wq,
                                                  const float* __restrict__ T2,
                                                  unsigned short* __restrict__ Ut) {
    __shared__ float As[16][17];
    __shared__ float Bs[16][17];
    const int tx = threadIdx.x, ty = threadIdx.y;
    const int i = blockIdx.y * 16 + ty;   // a: row of U  (k-index of big GEMM)
    const int j = blockIdx.x * 16 + tx;   // b: col of U  (n-index of big GEMM)
    float acc = 0.f;
    for (int k0 = 0; k0 < EDIM; k0 += 16) {
        As[ty][tx] = Wq[(k0 + tx) * EDIM + i];
        Bs[ty][tx] = T2[(k0 + ty) * EDIM + j];
        __syncthreads();
#pragma unroll
        for (int p = 0; p < 16; ++p) acc += As[ty][p] * Bs[p][tx];
        __syncthreads();
    }
    Ut[j * EDIM + i] = f32_to_bf16(acc);
}

// ---------------------------------------------------------------------------
// out = LayerNorm(node @ U + node)  — MFMA bf16, LN fused in epilogue.
// Block: 256 thr = 4 waves; block tile 64 rows x 512 cols; wave w owns cols
// [w*128, w*128+128). MFMA 16x16x32. A from fp32 node (in-register cvt),
// B from bf16 U^T (contiguous 16B frags, L2-resident).
// ---------------------------------------------------------------------------
__global__ __launch_bounds__(256) void gemm_mfma_ln(const float* __restrict__ node,
                                                    const unsigned short* __restrict__ Ut,
                                                    const float* __restrict__ gamma,
                                                    const float* __restrict__ beta,
                                                    float* __restrict__ out) {
    __shared__ float lds_s[4][64];
    __shared__ float lds_q[4][64];
    __shared__ float lds_mu[64];
    __shared__ float lds_rs[64];

    const int t  = threadIdx.x;
    const int w  = t >> 6;        // wave 0..3
    const int l  = t & 63;
    const int lr = l & 15;        // A-row / B-col / C-col within fragment
    const int lk = l >> 4;        // k-group (0..3)
    const int m0 = blockIdx.x * 64;
    const int n0 = w * 128;

    f32x4 acc[4][8];
#pragma unroll
    for (int mi = 0; mi < 4; ++mi)
#pragma unroll
        for (int ni = 0; ni < 8; ++ni)
            acc[mi][ni] = (f32x4){0.f, 0.f, 0.f, 0.f};

    const float* arow[4];
#pragma unroll
    for (int mi = 0; mi < 4; ++mi) {
        int gr = m0 + mi * 16 + lr;
        if (gr > NROWS - 1) gr = NROWS - 1;
        arow[mi] = node + (size_t)gr * EDIM;
    }
    const unsigned short* brow[8];
#pragma unroll
    for (int ni = 0; ni < 8; ++ni)
        brow[ni] = Ut + (size_t)(n0 + ni * 16 + lr) * EDIM;

#pragma unroll 1
    for (int kk = 0; kk < EDIM / 32; ++kk) {
        const int kg = kk * 32 + lk * 8;
        s16x8 bfr[8], afr[4];
#pragma unroll
        for (int ni = 0; ni < 8; ++ni)
            bfr[ni] = *(const s16x8*)(brow[ni] + kg);
#pragma unroll
        for (int mi = 0; mi < 4; ++mi) {
            const float* p = arow[mi] + kg;
            float4 f0 = *(const float4*)p;
            float4 f1 = *(const float4*)(p + 4);
            s16x8 av;
            av[0] = (short)f32_to_bf16(f0.x); av[1] = (short)f32_to_bf16(f0.y);
            av[2] = (short)f32_to_bf16(f0.z); av[3] = (short)f32_to_bf16(f0.w);
            av[4] = (short)f32_to_bf16(f1.x); av[5] = (short)f32_to_bf16(f1.y);
            av[6] = (short)f32_to_bf16(f1.z); av[7] = (short)f32_to_bf16(f1.w);
            afr[mi] = av;
        }
#pragma unroll
        for (int mi = 0; mi < 4; ++mi)
#pragma unroll
            for (int ni = 0; ni < 8; ++ni)
                acc[mi][ni] = __builtin_amdgcn_mfma_f32_16x16x32_bf16(
                    afr[mi], bfr[ni], acc[mi][ni], 0, 0, 0);
    }

    // ---- epilogue: residual add ----
#pragma unroll
    for (int mi = 0; mi < 4; ++mi) {
#pragma unroll
        for (int j = 0; j < 4; ++j) {
            int gr = m0 + mi * 16 + lk * 4 + j;
            if (gr > NROWS - 1) gr = NROWS - 1;
            const float* rp = node + (size_t)gr * EDIM + n0 + lr;
#pragma unroll
            for (int ni = 0; ni < 8; ++ni)
                acc[mi][ni][j] += rp[ni * 16];
        }
    }

    // ---- per-row stats: in-lane sum over ni, shfl-xor over the 16-lane group
#pragma unroll
    for (int mi = 0; mi < 4; ++mi) {
#pragma unroll
        for (int j = 0; j < 4; ++j) {
            float s = 0.f, q = 0.f;
#pragma unroll
            for (int ni = 0; ni < 8; ++ni) {
                float v = acc[mi][ni][j];
                s += v; q += v * v;
            }
#pragma unroll
            for (int off = 1; off < 16; off <<= 1) {
                s += __shfl_xor(s, off);
                q += __shfl_xor(q, off);
            }
            if (lr == 0) {
                int rl = mi * 16 + lk * 4 + j;
                lds_s[w][rl] = s;
                lds_q[w][rl] = q;
            }
        }
    }
    __syncthreads();
    if (t < 64) {
        float s = lds_s[0][t] + lds_s[1][t] + lds_s[2][t] + lds_s[3][t];
        float q = lds_q[0][t] + lds_q[1][t] + lds_q[2][t] + lds_q[3][t];
        float mu  = s * (1.f / (float)EDIM);
        float var = q * (1.f / (float)EDIM) - mu * mu;
        lds_mu[t] = mu;
        lds_rs[t] = rsqrtf(var + 1e-6f);
    }
    __syncthreads();

    float gv[8], bv[8];
#pragma unroll
    for (int ni = 0; ni < 8; ++ni) {
        int c = n0 + ni * 16 + lr;
        gv[ni] = gamma[c];
        bv[ni] = beta[c];
    }

#pragma unroll
    for (int mi = 0; mi < 4; ++mi) {
#pragma unroll
        for (int j = 0; j < 4; ++j) {
            int rl = mi * 16 + lk * 4 + j;
            int gr = m0 + rl;
            if (gr < NROWS) {
                float mu = lds_mu[rl], rs = lds_rs[rl];
                float* op = out + (size_t)gr * EDIM + n0 + lr;
#pragma unroll
                for (int ni = 0; ni < 8; ++ni)
                    op[ni * 16] = (acc[mi][ni][j] - mu) * rs * gv[ni] + bv[ni];
            }
        }
    }
}

// ---------------------------------------------------------------------------
extern "C" void kernel_launch(void* const* d_in, const int* in_sizes, int n_in,
                              void* d_out, int out_size, void* d_ws, size_t ws_size,
                              hipStream_t stream) {
    const float* node  = (const float*)d_in[0];   // [N, E]
    const float* obs   = (const float*)d_in[1];   // [M, O]
    const float* Wq    = (const float*)d_in[2];   // [E, E]
    const float* Wk    = (const float*)d_in[3];   // [E, O]
    const float* Wv    = (const float*)d_in[4];   // [E, O]
    const float* gamma = (const float*)d_in[5];   // [E]
    const float* beta  = (const float*)d_in[6];   // [E]
    float* out = (float*)d_out;

    float* ws = (float*)d_ws;
    float*          G  = ws;                                 // 256*256 f32
    float*          T1 = G + ODIM * ODIM;                    // 256*512 f32
    float*          T2 = T1 + ODIM * EDIM;                   // 512*512 f32
    unsigned short* Ut = (unsigned short*)(T2 + EDIM * EDIM);// 512*512 bf16

    dim3 b16(16, 16);

    hipMemsetAsync((void*)G, 0, ODIM * ODIM * sizeof(float), stream);
    // G = obs^T obs (split-K x8, atomic accumulate)
    gram_splitk<<<dim3(16, 16, 8), b16, 0, stream>>>(obs, G);
    // T1 = G @ Wv^T          [256 x 512], K=256
    sgemm_t<0, 1><<<dim3(32, 16), b16, 0, stream>>>(G, Wv, T1, EDIM, ODIM, ODIM, ODIM);
    // T2 = Wk @ T1           [512 x 512], K=256
    sgemm_t<0, 0><<<dim3(32, 32), b16, 0, stream>>>(Wk, T1, T2, EDIM, ODIM, ODIM, EDIM);
    // Ut = (Wq^T @ T2)^T in bf16   [512 x 512]
    ugemm_bf16<<<dim3(32, 32), b16, 0, stream>>>(Wq, T2, Ut);
    // out = LN(node @ U + node)
    gemm_mfma_ln<<<dim3((NROWS + 63) / 64), 256, 0, stream>>>(node, Ut, gamma, beta, out);
}

// Round 3
// 142.722 us; speedup vs baseline: 3.6644x; 1.5738x over previous
//
#include <hip/hip_runtime.h>
#include <hip/hip_bf16.h>

#define NROWS 50000
#define MOBS  2048
#define EDIM  512
#define ODIM  256

typedef short s16x8 __attribute__((ext_vector_type(8)));
typedef float f32x4 __attribute__((ext_vector_type(4)));

__device__ __forceinline__ unsigned short f32_to_bf16(float f) {
    unsigned int u = __float_as_uint(f);
    u += 0x7fffu + ((u >> 16) & 1u);     // RNE (inputs finite/normal)
    return (unsigned short)(u >> 16);
}

// ---------------------------------------------------------------------------
// Small-chain GEMM: 64x64 tile, 256 thr, 4x4 micro-tile, optional split-K
// (atomicAdd, C must be pre-zeroed), optional frag-major bf16 output (+I).
//   C[i,j] = sum_k Aval(i,k)*Bval(k,j)
//   TA=0: Aval=A[i*lda+k]   TA=1: Aval=A[k*lda+i]
//   TB=0: Bval=B[k*ldb+j]   TB=1: Bval=B[j*ldb+k]
// FRAG=1: write bf16 at fragment-major layout for the main kernel's B-loads,
//         adding identity (residual fold). Requires SPLIT==1.
// ---------------------------------------------------------------------------
template <int TA, int TB, int SPLIT, int FRAG>
__global__ __launch_bounds__(256) void sgemm4(const float* __restrict__ A,
                                              const float* __restrict__ B,
                                              void* __restrict__ Cv,
                                              int NN, int KK, int lda, int ldb) {
    __shared__ float SA[16][68];
    __shared__ float SB[16][68];
    const int t  = threadIdx.x;
    const int tx = t & 15, ty = t >> 4;
    const int i0 = blockIdx.y * 64, j0 = blockIdx.x * 64;
    int k_lo = 0, k_hi = KK;
    if (SPLIT > 1) { int ch = KK / SPLIT; k_lo = blockIdx.z * ch; k_hi = k_lo + ch; }

    float acc[4][4];
#pragma unroll
    for (int a = 0; a < 4; ++a)
#pragma unroll
        for (int b = 0; b < 4; ++b) acc[a][b] = 0.f;

    for (int k0 = k_lo; k0 < k_hi; k0 += 16) {
#pragma unroll
        for (int r = 0; r < 4; ++r) {
            int idx = t + 256 * r;
            int mm, kk2;
            if (TA) { mm = idx & 63; kk2 = idx >> 6; }
            else    { kk2 = idx & 15; mm = idx >> 4; }
            SA[kk2][mm] = TA ? A[(size_t)(k0 + kk2) * lda + i0 + mm]
                             : A[(size_t)(i0 + mm) * lda + k0 + kk2];
        }
#pragma unroll
        for (int r = 0; r < 4; ++r) {
            int idx = t + 256 * r;
            int jj, kk2;
            if (TB) { kk2 = idx & 15; jj = idx >> 4; }
            else    { jj = idx & 63; kk2 = idx >> 6; }
            SB[kk2][jj] = TB ? B[(size_t)(j0 + jj) * ldb + k0 + kk2]
                             : B[(size_t)(k0 + kk2) * ldb + j0 + jj];
        }
        __syncthreads();
#pragma unroll
        for (int kk2 = 0; kk2 < 16; ++kk2) {
            float4 a4 = *(const float4*)&SA[kk2][ty * 4];
            float4 b4 = *(const float4*)&SB[kk2][tx * 4];
            float av[4] = {a4.x, a4.y, a4.z, a4.w};
            float bv[4] = {b4.x, b4.y, b4.z, b4.w};
#pragma unroll
            for (int a = 0; a < 4; ++a)
#pragma unroll
                for (int b = 0; b < 4; ++b) acc[a][b] += av[a] * bv[b];
        }
        __syncthreads();
    }

    if (FRAG) {
        unsigned short* C = (unsigned short*)Cv;
#pragma unroll
        for (int a = 0; a < 4; ++a)
#pragma unroll
            for (int b = 0; b < 4; ++b) {
                int i = i0 + ty * 4 + a;       // k-dim of main GEMM
                int j = j0 + tx * 4 + b;       // col of main GEMM
                float v = acc[a][b] + (i == j ? 1.f : 0.f);
                int f = j >> 4, lr = j & 15, kk = i >> 5, lk = (i >> 3) & 3;
                C[((size_t)((f * 16 + kk) * 64 + lk * 16 + lr)) * 8 + (i & 7)] =
                    f32_to_bf16(v);
            }
    } else if (SPLIT > 1) {
        float* C = (float*)Cv;
#pragma unroll
        for (int a = 0; a < 4; ++a)
#pragma unroll
            for (int b = 0; b < 4; ++b)
                atomicAdd(&C[(size_t)(i0 + ty * 4 + a) * NN + j0 + tx * 4 + b],
                          acc[a][b]);
    } else {
        float* C = (float*)Cv;
#pragma unroll
        for (int a = 0; a < 4; ++a) {
            float4 o = make_float4(acc[a][0], acc[a][1], acc[a][2], acc[a][3]);
            *(float4*)&C[(size_t)(i0 + ty * 4 + a) * NN + j0 + tx * 4] = o;
        }
    }
}

// ---------------------------------------------------------------------------
// out = LayerNorm(node @ (U+I))   [residual folded into U's diagonal]
// Block: 256 thr = 4 waves, tile 64 rows x 512 cols (full row -> fused LN).
// A: node staged once to LDS as bf16 (XOR-swizzled), coalesced float4 reads.
// B: frag-major bf16 U (L2-resident), contiguous 1KB wave loads, reg dbuf.
// K-loop is barrier-free after the single staging barrier.
// ---------------------------------------------------------------------------
__global__ __launch_bounds__(256, 2) void gemm_mfma_ln(
    const float* __restrict__ node, const unsigned short* __restrict__ Uf,
    const float* __restrict__ gamma, const float* __restrict__ beta,
    float* __restrict__ out) {
    __shared__ unsigned short As[64 * 512];   // 64 KB; reused for LN stats
    float* lds_s  = (float*)As;               // [4][64]
    float* lds_q  = (float*)As + 256;         // [4][64]
    float* lds_mu = (float*)As + 512;         // [64]
    float* lds_rs = (float*)As + 576;         // [64]

    const int t  = threadIdx.x;
    const int w  = t >> 6;        // wave 0..3
    const int l  = t & 63;
    const int lr = l & 15;
    const int lk = l >> 4;
    const int m0 = blockIdx.x * 64;

    // ---- stage A: 64 rows x 512 cols fp32 -> bf16 LDS, swizzled ----
#pragma unroll 4
    for (int rb = 0; rb < 16; ++rb) {
        int row = rb * 4 + w;                 // one full row per wave
        int gr = m0 + row;
        if (gr > NROWS - 1) gr = NROWS - 1;
        const float4* p = (const float4*)(node + (size_t)gr * EDIM + l * 8);
        float4 f0 = p[0], f1 = p[1];
        s16x8 av;
        av[0] = (short)f32_to_bf16(f0.x); av[1] = (short)f32_to_bf16(f0.y);
        av[2] = (short)f32_to_bf16(f0.z); av[3] = (short)f32_to_bf16(f0.w);
        av[4] = (short)f32_to_bf16(f1.x); av[5] = (short)f32_to_bf16(f1.y);
        av[6] = (short)f32_to_bf16(f1.z); av[7] = (short)f32_to_bf16(f1.w);
        int byte = row * 1024 + ((l * 16) ^ ((row & 7) << 4));
        *(s16x8*)((char*)As + byte) = av;
    }
    __syncthreads();

    f32x4 acc[4][8];
#pragma unroll
    for (int mi = 0; mi < 4; ++mi)
#pragma unroll
        for (int ni = 0; ni < 8; ++ni)
            acc[mi][ni] = (f32x4){0.f, 0.f, 0.f, 0.f};

    // per-wave B base: wave w owns n-frags f = w*8 + ni
    const unsigned short* bw = Uf + (size_t)w * 65536 + (size_t)l * 8;

    s16x8 bfr[2][8];
#pragma unroll
    for (int ni = 0; ni < 8; ++ni)
        bfr[0][ni] = *(const s16x8*)(bw + (size_t)ni * 8192);

#pragma unroll
    for (int kk = 0; kk < 16; ++kk) {
        const int cur = kk & 1, nxt = cur ^ 1;
        if (kk < 15) {
#pragma unroll
            for (int ni = 0; ni < 8; ++ni)
                bfr[nxt][ni] =
                    *(const s16x8*)(bw + (size_t)ni * 8192 + (kk + 1) * 512);
        }
        s16x8 afr[4];
#pragma unroll
        for (int mi = 0; mi < 4; ++mi) {
            int row = mi * 16 + lr;
            int byte = row * 1024 + ((kk * 64 + lk * 16) ^ ((row & 7) << 4));
            afr[mi] = *(const s16x8*)((const char*)As + byte);
        }
#pragma unroll
        for (int mi = 0; mi < 4; ++mi)
#pragma unroll
            for (int ni = 0; ni < 8; ++ni)
                acc[mi][ni] = __builtin_amdgcn_mfma_f32_16x16x32_bf16(
                    afr[mi], bfr[cur][ni], acc[mi][ni], 0, 0, 0);
    }

    __syncthreads();   // As dead; its memory becomes the LN stats buffers

    // ---- per-row stats ----
#pragma unroll
    for (int mi = 0; mi < 4; ++mi) {
#pragma unroll
        for (int j = 0; j < 4; ++j) {
            float s = 0.f, q = 0.f;
#pragma unroll
            for (int ni = 0; ni < 8; ++ni) {
                float v = acc[mi][ni][j];
                s += v; q += v * v;
            }
#pragma unroll
            for (int off = 1; off < 16; off <<= 1) {
                s += __shfl_xor(s, off);
                q += __shfl_xor(q, off);
            }
            if (lr == 0) {
                int rl = mi * 16 + lk * 4 + j;
                lds_s[w * 64 + rl] = s;
                lds_q[w * 64 + rl] = q;
            }
        }
    }
    __syncthreads();
    if (t < 64) {
        float s = lds_s[t] + lds_s[64 + t] + lds_s[128 + t] + lds_s[192 + t];
        float q = lds_q[t] + lds_q[64 + t] + lds_q[128 + t] + lds_q[192 + t];
        float mu  = s * (1.f / (float)EDIM);
        float var = q * (1.f / (float)EDIM) - mu * mu;
        lds_mu[t] = mu;
        lds_rs[t] = rsqrtf(var + 1e-6f);
    }
    __syncthreads();

    const int n0 = w * 128;
    float gv[8], bv[8];
#pragma unroll
    for (int ni = 0; ni < 8; ++ni) {
        int c = n0 + ni * 16 + lr;
        gv[ni] = gamma[c];
        bv[ni] = beta[c];
    }

#pragma unroll
    for (int mi = 0; mi < 4; ++mi) {
#pragma unroll
        for (int j = 0; j < 4; ++j) {
            int rl = mi * 16 + lk * 4 + j;
            int gr = m0 + rl;
            if (gr < NROWS) {
                float mu = lds_mu[rl], rs = lds_rs[rl];
                float* op = out + (size_t)gr * EDIM + n0 + lr;
#pragma unroll
                for (int ni = 0; ni < 8; ++ni)
                    op[ni * 16] = (acc[mi][ni][j] - mu) * rs * gv[ni] + bv[ni];
            }
        }
    }
}

// ---------------------------------------------------------------------------
extern "C" void kernel_launch(void* const* d_in, const int* in_sizes, int n_in,
                              void* d_out, int out_size, void* d_ws, size_t ws_size,
                              hipStream_t stream) {
    const float* node  = (const float*)d_in[0];   // [N, E]
    const float* obs   = (const float*)d_in[1];   // [M, O]
    const float* Wq    = (const float*)d_in[2];   // [E, E]
    const float* Wk    = (const float*)d_in[3];   // [E, O]
    const float* Wv    = (const float*)d_in[4];   // [E, O]
    const float* gamma = (const float*)d_in[5];   // [E]
    const float* beta  = (const float*)d_in[6];   // [E]
    float* out = (float*)d_out;

    float* ws = (float*)d_ws;
    float*          G  = ws;                        // [256,256] f32
    float*          P  = G  + ODIM * ODIM;          // [512,256] f32  (Wq^T Wk)
    float*          PG = P  + EDIM * ODIM;          // [512,256] f32
    unsigned short* Uf = (unsigned short*)(PG + EDIM * ODIM); // frag-major bf16

    // zero the three split-K / accumulated buffers in one shot
    hipMemsetAsync((void*)G, 0,
                   (ODIM * ODIM + 2 * EDIM * ODIM) * sizeof(float), stream);

    // G = obs^T obs            [256,256] K=2048, split-K 16
    sgemm4<1, 0, 16, 0><<<dim3(4, 4, 16), 256, 0, stream>>>(obs, obs, G, ODIM, MOBS, ODIM, ODIM);
    // P = Wq^T @ Wk            [512,256] K=512, split-K 4
    sgemm4<1, 0, 4, 0><<<dim3(4, 8, 4), 256, 0, stream>>>(Wq, Wk, P, ODIM, EDIM, EDIM, ODIM);
    // PG = P @ G               [512,256] K=256, split-K 2
    sgemm4<0, 0, 2, 0><<<dim3(4, 8, 2), 256, 0, stream>>>(P, G, PG, ODIM, ODIM, ODIM, ODIM);
    // Uf = frag(PG @ Wv^T + I) [512,512] K=256, bf16 frag-major
    sgemm4<0, 1, 1, 1><<<dim3(8, 8, 1), 256, 0, stream>>>(PG, Wv, Uf, EDIM, ODIM, ODIM, ODIM);
    // out = LN(node @ (U+I))
    gemm_mfma_ln<<<dim3((NROWS + 63) / 64), 256, 0, stream>>>(node, Uf, gamma, beta, out);
}

// Round 4
// 129.623 us; speedup vs baseline: 4.0347x; 1.1011x over previous
//
#include <hip/hip_runtime.h>
#include <hip/hip_bf16.h>

#define NROWS 50000
#define MOBS  2048
#define EDIM  512
#define ODIM  256

typedef short s16x8 __attribute__((ext_vector_type(8)));
typedef float f32x4 __attribute__((ext_vector_type(4)));

__device__ __forceinline__ unsigned short f32_to_bf16(float f) {
    unsigned int u = __float_as_uint(f);
    u += 0x7fffu + ((u >> 16) & 1u);     // RNE (inputs finite/normal)
    return (unsigned short)(u >> 16);
}

// ---------------------------------------------------------------------------
// Fused first stage: G = obs^T obs (z<16, split-K 16) and P = Wq^T Wk
// (z>=16, split-K 4). Both are X^T Y GEMMs, 64x64 tiles, atomicAdd output.
// grid(4, 8, 20); G-part masks blockIdx.y < 4.
// ---------------------------------------------------------------------------
__global__ __launch_bounds__(256) void gp_fused(const float* __restrict__ obs,
                                                const float* __restrict__ Wq,
                                                const float* __restrict__ Wk,
                                                float* __restrict__ G,
                                                float* __restrict__ P) {
    __shared__ float SA[16][68];
    __shared__ float SB[16][68];
    const float *A, *B;
    float* C;
    int lda, ldb, k_lo, k_hi;
    const int bz = blockIdx.z;
    if (bz < 16) {
        if (blockIdx.y >= 4) return;
        A = obs; B = obs; C = G; lda = ODIM; ldb = ODIM;
        k_lo = bz * (MOBS / 16); k_hi = k_lo + MOBS / 16;
    } else {
        A = Wq; B = Wk; C = P; lda = EDIM; ldb = ODIM;
        k_lo = (bz - 16) * (EDIM / 4); k_hi = k_lo + EDIM / 4;
    }
    const int t  = threadIdx.x;
    const int tx = t & 15, ty = t >> 4;
    const int i0 = blockIdx.y * 64, j0 = blockIdx.x * 64;

    float acc[4][4];
#pragma unroll
    for (int a = 0; a < 4; ++a)
#pragma unroll
        for (int b = 0; b < 4; ++b) acc[a][b] = 0.f;

    for (int k0 = k_lo; k0 < k_hi; k0 += 16) {
#pragma unroll
        for (int r = 0; r < 4; ++r) {
            int idx = t + 256 * r;
            int mm = idx & 63, kk2 = idx >> 6;
            SA[kk2][mm] = A[(size_t)(k0 + kk2) * lda + i0 + mm];
        }
#pragma unroll
        for (int r = 0; r < 4; ++r) {
            int idx = t + 256 * r;
            int jj = idx & 63, kk2 = idx >> 6;
            SB[kk2][jj] = B[(size_t)(k0 + kk2) * ldb + j0 + jj];
        }
        __syncthreads();
#pragma unroll
        for (int kk2 = 0; kk2 < 16; ++kk2) {
            float4 a4 = *(const float4*)&SA[kk2][ty * 4];
            float4 b4 = *(const float4*)&SB[kk2][tx * 4];
            float av[4] = {a4.x, a4.y, a4.z, a4.w};
            float bv[4] = {b4.x, b4.y, b4.z, b4.w};
#pragma unroll
            for (int a = 0; a < 4; ++a)
#pragma unroll
                for (int b = 0; b < 4; ++b) acc[a][b] += av[a] * bv[b];
        }
        __syncthreads();
    }
#pragma unroll
    for (int a = 0; a < 4; ++a)
#pragma unroll
        for (int b = 0; b < 4; ++b)
            atomicAdd(&C[(size_t)(i0 + ty * 4 + a) * ODIM + j0 + tx * 4 + b],
                      acc[a][b]);
}

// ---------------------------------------------------------------------------
// Small-chain GEMM (as R3): 64x64 tile, 4x4 micro-tile, split-K / frag out.
// ---------------------------------------------------------------------------
template <int TA, int TB, int SPLIT, int FRAG>
__global__ __launch_bounds__(256) void sgemm4(const float* __restrict__ A,
                                              const float* __restrict__ B,
                                              void* __restrict__ Cv,
                                              int NN, int KK, int lda, int ldb) {
    __shared__ float SA[16][68];
    __shared__ float SB[16][68];
    const int t  = threadIdx.x;
    const int tx = t & 15, ty = t >> 4;
    const int i0 = blockIdx.y * 64, j0 = blockIdx.x * 64;
    int k_lo = 0, k_hi = KK;
    if (SPLIT > 1) { int ch = KK / SPLIT; k_lo = blockIdx.z * ch; k_hi = k_lo + ch; }

    float acc[4][4];
#pragma unroll
    for (int a = 0; a < 4; ++a)
#pragma unroll
        for (int b = 0; b < 4; ++b) acc[a][b] = 0.f;

    for (int k0 = k_lo; k0 < k_hi; k0 += 16) {
#pragma unroll
        for (int r = 0; r < 4; ++r) {
            int idx = t + 256 * r;
            int mm, kk2;
            if (TA) { mm = idx & 63; kk2 = idx >> 6; }
            else    { kk2 = idx & 15; mm = idx >> 4; }
            SA[kk2][mm] = TA ? A[(size_t)(k0 + kk2) * lda + i0 + mm]
                             : A[(size_t)(i0 + mm) * lda + k0 + kk2];
        }
#pragma unroll
        for (int r = 0; r < 4; ++r) {
            int idx = t + 256 * r;
            int jj, kk2;
            if (TB) { kk2 = idx & 15; jj = idx >> 4; }
            else    { jj = idx & 63; kk2 = idx >> 6; }
            SB[kk2][jj] = TB ? B[(size_t)(j0 + jj) * ldb + k0 + kk2]
                             : B[(size_t)(k0 + kk2) * ldb + j0 + jj];
        }
        __syncthreads();
#pragma unroll
        for (int kk2 = 0; kk2 < 16; ++kk2) {
            float4 a4 = *(const float4*)&SA[kk2][ty * 4];
            float4 b4 = *(const float4*)&SB[kk2][tx * 4];
            float av[4] = {a4.x, a4.y, a4.z, a4.w};
            float bv[4] = {b4.x, b4.y, b4.z, b4.w};
#pragma unroll
            for (int a = 0; a < 4; ++a)
#pragma unroll
                for (int b = 0; b < 4; ++b) acc[a][b] += av[a] * bv[b];
        }
        __syncthreads();
    }

    if (FRAG) {
        unsigned short* C = (unsigned short*)Cv;
#pragma unroll
        for (int a = 0; a < 4; ++a)
#pragma unroll
            for (int b = 0; b < 4; ++b) {
                int i = i0 + ty * 4 + a;       // k-dim of main GEMM
                int j = j0 + tx * 4 + b;       // col of main GEMM
                float v = acc[a][b] + (i == j ? 1.f : 0.f);
                int f = j >> 4, lr = j & 15, kk = i >> 5, lk = (i >> 3) & 3;
                C[((size_t)((f * 16 + kk) * 64 + lk * 16 + lr)) * 8 + (i & 7)] =
                    f32_to_bf16(v);
            }
    } else if (SPLIT > 1) {
        float* C = (float*)Cv;
#pragma unroll
        for (int a = 0; a < 4; ++a)
#pragma unroll
            for (int b = 0; b < 4; ++b)
                atomicAdd(&C[(size_t)(i0 + ty * 4 + a) * NN + j0 + tx * 4 + b],
                          acc[a][b]);
    } else {
        float* C = (float*)Cv;
#pragma unroll
        for (int a = 0; a < 4; ++a) {
            float4 o = make_float4(acc[a][0], acc[a][1], acc[a][2], acc[a][3]);
            *(float4*)&C[(size_t)(i0 + ty * 4 + a) * NN + j0 + tx * 4] = o;
        }
    }
}

// ---------------------------------------------------------------------------
// out = LayerNorm(node @ (U+I))   [residual folded into U's diagonal]
// Block: 512 thr = 8 waves, tile 64 rows x 512 cols; wave w owns cols
// [w*64, w*64+64) for all 64 rows (4 m-frags x 4 n-frags, acc = 64 VGPR).
// A: node staged once to LDS as bf16 (XOR-swizzled). B: frag-major bf16 U
// (L2-resident), contiguous 1KB wave loads, register double-buffered.
// 2 blocks/CU (64KB LDS) x 8 waves = 16 waves/CU target occupancy.
// ---------------------------------------------------------------------------
__global__ __launch_bounds__(512, 4) void gemm_mfma_ln(
    const float* __restrict__ node, const unsigned short* __restrict__ Uf,
    const float* __restrict__ gamma, const float* __restrict__ beta,
    float* __restrict__ out) {
    __shared__ unsigned short As[64 * 512];   // 64 KB; reused for LN stats
    float* lds_s  = (float*)As;               // [8][64]
    float* lds_q  = (float*)As + 512;         // [8][64]
    float* lds_mu = (float*)As + 1024;        // [64]
    float* lds_rs = (float*)As + 1088;        // [64]

    const int t  = threadIdx.x;
    const int w  = t >> 6;        // wave 0..7
    const int l  = t & 63;
    const int lr = l & 15;
    const int lk = l >> 4;
    const int m0 = blockIdx.x * 64;

    // ---- stage A: 64 rows x 512 cols fp32 -> bf16 LDS, swizzled ----
#pragma unroll
    for (int it = 0; it < 8; ++it) {
        int row = it * 8 + w;                 // one full row per wave
        int gr = m0 + row;
        if (gr > NROWS - 1) gr = NROWS - 1;
        const float4* p = (const float4*)(node + (size_t)gr * EDIM + l * 8);
        float4 f0 = p[0], f1 = p[1];
        s16x8 av;
        av[0] = (short)f32_to_bf16(f0.x); av[1] = (short)f32_to_bf16(f0.y);
        av[2] = (short)f32_to_bf16(f0.z); av[3] = (short)f32_to_bf16(f0.w);
        av[4] = (short)f32_to_bf16(f1.x); av[5] = (short)f32_to_bf16(f1.y);
        av[6] = (short)f32_to_bf16(f1.z); av[7] = (short)f32_to_bf16(f1.w);
        int byte = row * 1024 + ((l * 16) ^ ((row & 7) << 4));
        *(s16x8*)((char*)As + byte) = av;
    }
    __syncthreads();

    f32x4 acc[4][4];
#pragma unroll
    for (int mi = 0; mi < 4; ++mi)
#pragma unroll
        for (int ni = 0; ni < 4; ++ni)
            acc[mi][ni] = (f32x4){0.f, 0.f, 0.f, 0.f};

    // wave w owns n-frags f = w*4 + ni; frag (f,kk) base = (f*16+kk)*512 + l*8
    const unsigned short* bw = Uf + (size_t)w * 32768 + (size_t)l * 8;

    s16x8 bfr[2][4];
#pragma unroll
    for (int ni = 0; ni < 4; ++ni)
        bfr[0][ni] = *(const s16x8*)(bw + (size_t)ni * 8192);

#pragma unroll
    for (int kk = 0; kk < 16; ++kk) {
        const int cur = kk & 1, nxt = cur ^ 1;
        if (kk < 15) {
#pragma unroll
            for (int ni = 0; ni < 4; ++ni)
                bfr[nxt][ni] =
                    *(const s16x8*)(bw + (size_t)ni * 8192 + (kk + 1) * 512);
        }
        s16x8 afr[4];
#pragma unroll
        for (int mi = 0; mi < 4; ++mi) {
            int row = mi * 16 + lr;
            int byte = row * 1024 + ((kk * 64 + lk * 16) ^ ((row & 7) << 4));
            afr[mi] = *(const s16x8*)((const char*)As + byte);
        }
#pragma unroll
        for (int mi = 0; mi < 4; ++mi)
#pragma unroll
            for (int ni = 0; ni < 4; ++ni)
                acc[mi][ni] = __builtin_amdgcn_mfma_f32_16x16x32_bf16(
                    afr[mi], bfr[cur][ni], acc[mi][ni], 0, 0, 0);
    }

    __syncthreads();   // As dead; its memory becomes the LN stats buffers

    // ---- per-row stats: sum over ni in-lane, shfl-xor over 16-lane group ----
#pragma unroll
    for (int mi = 0; mi < 4; ++mi) {
#pragma unroll
        for (int j = 0; j < 4; ++j) {
            float s = 0.f, q = 0.f;
#pragma unroll
            for (int ni = 0; ni < 4; ++ni) {
                float v = acc[mi][ni][j];
                s += v; q += v * v;
            }
#pragma unroll
            for (int off = 1; off < 16; off <<= 1) {
                s += __shfl_xor(s, off);
                q += __shfl_xor(q, off);
            }
            if (lr == 0) {
                int rl = mi * 16 + lk * 4 + j;
                lds_s[w * 64 + rl] = s;
                lds_q[w * 64 + rl] = q;
            }
        }
    }
    __syncthreads();
    if (t < 64) {
        float s = 0.f, q = 0.f;
#pragma unroll
        for (int ww = 0; ww < 8; ++ww) {
            s += lds_s[ww * 64 + t];
            q += lds_q[ww * 64 + t];
        }
        float mu  = s * (1.f / (float)EDIM);
        float var = q * (1.f / (float)EDIM) - mu * mu;
        lds_mu[t] = mu;
        lds_rs[t] = rsqrtf(var + 1e-6f);
    }
    __syncthreads();

    const int n0 = w * 64;
    float gv[4], bv[4];
#pragma unroll
    for (int ni = 0; ni < 4; ++ni) {
        int c = n0 + ni * 16 + lr;
        gv[ni] = gamma[c];
        bv[ni] = beta[c];
    }

#pragma unroll
    for (int mi = 0; mi < 4; ++mi) {
#pragma unroll
        for (int j = 0; j < 4; ++j) {
            int rl = mi * 16 + lk * 4 + j;
            int gr = m0 + rl;
            if (gr < NROWS) {
                float mu = lds_mu[rl], rs = lds_rs[rl];
                float* op = out + (size_t)gr * EDIM + n0 + lr;
#pragma unroll
                for (int ni = 0; ni < 4; ++ni)
                    op[ni * 16] = (acc[mi][ni][j] - mu) * rs * gv[ni] + bv[ni];
            }
        }
    }
}

// ---------------------------------------------------------------------------
extern "C" void kernel_launch(void* const* d_in, const int* in_sizes, int n_in,
                              void* d_out, int out_size, void* d_ws, size_t ws_size,
                              hipStream_t stream) {
    const float* node  = (const float*)d_in[0];   // [N, E]
    const float* obs   = (const float*)d_in[1];   // [M, O]
    const float* Wq    = (const float*)d_in[2];   // [E, E]
    const float* Wk    = (const float*)d_in[3];   // [E, O]
    const float* Wv    = (const float*)d_in[4];   // [E, O]
    const float* gamma = (const float*)d_in[5];   // [E]
    const float* beta  = (const float*)d_in[6];   // [E]
    float* out = (float*)d_out;

    float* ws = (float*)d_ws;
    float*          G  = ws;                        // [256,256] f32
    float*          P  = G  + ODIM * ODIM;          // [512,256] f32  (Wq^T Wk)
    float*          PG = P  + EDIM * ODIM;          // [512,256] f32
    unsigned short* Uf = (unsigned short*)(PG + EDIM * ODIM); // frag-major bf16

    // zero G, P, PG (split-K accumulators) in one shot
    hipMemsetAsync((void*)G, 0,
                   (ODIM * ODIM + 2 * EDIM * ODIM) * sizeof(float), stream);

    // G = obs^T obs (split-K 16)  AND  P = Wq^T Wk (split-K 4), fused
    gp_fused<<<dim3(4, 8, 20), 256, 0, stream>>>(obs, Wq, Wk, G, P);
    // PG = P @ G               [512,256] K=256, split-K 2
    sgemm4<0, 0, 2, 0><<<dim3(4, 8, 2), 256, 0, stream>>>(P, G, PG, ODIM, ODIM, ODIM, ODIM);
    // Uf = frag(PG @ Wv^T + I) [512,512] K=256, bf16 frag-major
    sgemm4<0, 1, 1, 1><<<dim3(8, 8, 1), 256, 0, stream>>>(PG, Wv, Uf, EDIM, ODIM, ODIM, ODIM);
    // out = LN(node @ (U+I))
    gemm_mfma_ln<<<dim3((NROWS + 63) / 64), 512, 0, stream>>>(node, Uf, gamma, beta, out);
}